// Round 1
// baseline (48.492 us; speedup 1.0000x reference)
//
#include <hip/hip_runtime.h>
#include <math.h>

#define N9   6000
#define N10  9000
#define FDIM 128
#define ALPHA 0.2f
#define MAXNBR 1024

// ---------------------------------------------------------------------------
// Kernel A: per-node dot products with attention vector halves.
//   query rows -> qa1 = q.a1, qa2 = q.a2
//   key rows   -> ka2 = k.a2
// One wave (64 threads) per node; each lane handles 2 of the 128 features.
// ---------------------------------------------------------------------------
__global__ __launch_bounds__(64)
void gat_dots_kernel(const int* __restrict__ version,
                     const float* __restrict__ U9,
                     const float* __restrict__ U10,
                     const float* __restrict__ a,
                     float* __restrict__ qa1,
                     float* __restrict__ qa2,
                     float* __restrict__ ka2) {
    const int v  = version[0];
    const int nq = v ? N10 : N9;
    const int nk = v ? N9  : N10;
    const float* __restrict__ Q = v ? U10 : U9;
    const float* __restrict__ K = v ? U9  : U10;
    const float* __restrict__ a1 = a;
    const float* __restrict__ a2 = a + FDIM;

    const int row  = blockIdx.x;
    const int lane = threadIdx.x;  // 0..63

    if (row < nq) {
        const float* x = Q + (size_t)row * FDIM;
        float x0 = x[lane], x1 = x[lane + 64];
        float s1 = x0 * a1[lane] + x1 * a1[lane + 64];
        float s2 = x0 * a2[lane] + x1 * a2[lane + 64];
        #pragma unroll
        for (int o = 32; o > 0; o >>= 1) {
            s1 += __shfl_down(s1, o);
            s2 += __shfl_down(s2, o);
        }
        if (lane == 0) { qa1[row] = s1; qa2[row] = s2; }
    } else {
        const int r = row - nq;
        if (r < nk) {
            const float* x = K + (size_t)r * FDIM;
            float s2 = x[lane] * a2[lane] + x[lane + 64] * a2[lane + 64];
            #pragma unroll
            for (int o = 32; o > 0; o >>= 1) s2 += __shfl_down(s2, o);
            if (lane == 0) ka2[r] = s2;
        }
    }
}

// ---------------------------------------------------------------------------
// Kernel B: one block per query row.
//   Phase 1: coalesced float4 scan of the adjacency row; push nonzero (j, e)
//            into an LDS neighbor list (avg degree ~4).
//   Phase 2: thread 0 computes the stable softmax over {self} U neighbors.
//   Phase 3: 128 threads accumulate h[f] = w_self*q[f] + sum_j w_j*k[j][f],
//            apply elu, write out.
// ---------------------------------------------------------------------------
__global__ __launch_bounds__(256)
void gat_row_kernel(const int* __restrict__ version,
                    const float* __restrict__ U9,
                    const float* __restrict__ U10,
                    const float* __restrict__ adj9to10,
                    const float* __restrict__ adj10to9,
                    const float* __restrict__ qa1,
                    const float* __restrict__ qa2,
                    const float* __restrict__ ka2,
                    float* __restrict__ out) {
    const int v  = version[0];
    const int nq = v ? N10 : N9;
    const int nk = v ? N9  : N10;
    const int i  = blockIdx.x;
    if (i >= nq) return;

    const float* __restrict__ Q   = v ? U10 : U9;
    const float* __restrict__ K   = v ? U9  : U10;
    const float* __restrict__ adj = (v ? adj10to9 : adj9to10) + (size_t)i * nk;

    __shared__ int   s_cnt;
    __shared__ float s_wself;
    __shared__ int   s_j[MAXNBR];
    __shared__ float s_e[MAXNBR];
    __shared__ float s_w[MAXNBR];

    const int t = threadIdx.x;
    if (t == 0) s_cnt = 0;
    __syncthreads();

    const float qa1i = qa1[i];

    // Phase 1: scan adjacency row (nk divisible by 4)
    const float4* __restrict__ adj4 = (const float4*)adj;
    const int n4 = nk >> 2;
    for (int p = t; p < n4; p += 256) {
        float4 vv = adj4[p];
        if (vv.x > 0.f || vv.y > 0.f || vv.z > 0.f || vv.w > 0.f) {
            float va[4] = {vv.x, vv.y, vv.z, vv.w};
            #pragma unroll
            for (int c = 0; c < 4; ++c) {
                if (va[c] > 0.f) {
                    int idx = atomicAdd(&s_cnt, 1);
                    if (idx < MAXNBR) {
                        int j = p * 4 + c;
                        float e = qa1i + ka2[j];
                        e = (e >= 0.f) ? e : ALPHA * e;
                        s_j[idx] = j;
                        s_e[idx] = e;
                    }
                }
            }
        }
    }
    __syncthreads();

    const int cnt = (s_cnt < MAXNBR) ? s_cnt : MAXNBR;

    // Phase 2: small softmax (self entry always unmasked -> no NaN path)
    if (t == 0) {
        float se = qa1i + qa2[i];
        se = (se >= 0.f) ? se : ALPHA * se;
        float m = se;
        for (int c = 0; c < cnt; ++c) m = fmaxf(m, s_e[c]);
        float wself = expf(se - m);
        float wsum  = wself;
        for (int c = 0; c < cnt; ++c) {
            float w = expf(s_e[c] - m);
            s_w[c] = w;
            wsum += w;
        }
        float inv = 1.f / wsum;
        s_wself = wself * inv;
        for (int c = 0; c < cnt; ++c) s_w[c] *= inv;
    }
    __syncthreads();

    // Phase 3: weighted feature accumulation + elu
    if (t < FDIM) {
        float h = s_wself * Q[(size_t)i * FDIM + t];
        for (int c = 0; c < cnt; ++c) {
            h += s_w[c] * K[(size_t)s_j[c] * FDIM + t];
        }
        h = (h > 0.f) ? h : expm1f(h);
        out[(size_t)i * FDIM + t] = h;
    }
}

extern "C" void kernel_launch(void* const* d_in, const int* in_sizes, int n_in,
                              void* d_out, int out_size, void* d_ws, size_t ws_size,
                              hipStream_t stream) {
    const int*   d_version = (const int*)d_in[0];
    const float* d_U9      = (const float*)d_in[1];
    const float* d_U10     = (const float*)d_in[2];
    const float* d_a       = (const float*)d_in[3];
    const float* d_adj9    = (const float*)d_in[4];
    const float* d_adj10   = (const float*)d_in[5];
    float*       d_o       = (float*)d_out;

    // Workspace layout (floats): qa1[9000] | qa2[9000] | ka2[9000]
    float* w_qa1 = (float*)d_ws;
    float* w_qa2 = w_qa1 + N10;
    float* w_ka2 = w_qa2 + N10;

    // Kernel A: dots for all query + key nodes (N9 + N10 blocks covers both
    // version branches; extents resolved on-device).
    gat_dots_kernel<<<N9 + N10, 64, 0, stream>>>(
        d_version, d_U9, d_U10, d_a, w_qa1, w_qa2, w_ka2);

    // Kernel B: one block per query row; grid covers max(N9, N10).
    gat_row_kernel<<<N10, 256, 0, stream>>>(
        d_version, d_U9, d_U10, d_adj9, d_adj10,
        w_qa1, w_qa2, w_ka2, d_o);
}

// Round 2
// 48.378 us; speedup vs baseline: 1.0024x; 1.0024x over previous
//
#include <hip/hip_runtime.h>
#include <math.h>

#define N9   6000
#define N10  9000
#define FDIM 128
#define ALPHA 0.2f
#define MAXNBR 128
#define ROWBLOCKS 2048

// ---------------------------------------------------------------------------
// Kernel A: per-node dot products with attention vector halves.
//   query rows -> qa1 = q.a1, qa2 = q.a2
//   key rows   -> ka2 = k.a2
// One wave (64 threads) per node; each lane handles 2 of the 128 features.
// ---------------------------------------------------------------------------
__global__ __launch_bounds__(64)
void gat_dots_kernel(const int* __restrict__ version,
                     const float* __restrict__ U9,
                     const float* __restrict__ U10,
                     const float* __restrict__ a,
                     float* __restrict__ qa1,
                     float* __restrict__ qa2,
                     float* __restrict__ ka2) {
    const int v  = version[0];
    const int nq = v ? N10 : N9;
    const int nk = v ? N9  : N10;
    const float* __restrict__ Q = v ? U10 : U9;
    const float* __restrict__ K = v ? U9  : U10;
    const float* __restrict__ a1 = a;
    const float* __restrict__ a2 = a + FDIM;

    const int row  = blockIdx.x;
    const int lane = threadIdx.x;  // 0..63

    if (row < nq) {
        const float* x = Q + (size_t)row * FDIM;
        float x0 = x[lane], x1 = x[lane + 64];
        float s1 = x0 * a1[lane] + x1 * a1[lane + 64];
        float s2 = x0 * a2[lane] + x1 * a2[lane + 64];
        #pragma unroll
        for (int o = 32; o > 0; o >>= 1) {
            s1 += __shfl_down(s1, o);
            s2 += __shfl_down(s2, o);
        }
        if (lane == 0) { qa1[row] = s1; qa2[row] = s2; }
    } else {
        const int r = row - nq;
        if (r < nk) {
            const float* x = K + (size_t)r * FDIM;
            float s2 = x[lane] * a2[lane] + x[lane + 64] * a2[lane + 64];
            #pragma unroll
            for (int o = 32; o > 0; o >>= 1) s2 += __shfl_down(s2, o);
            if (lane == 0) ka2[r] = s2;
        }
    }
}

// ---------------------------------------------------------------------------
// Kernel B: persistent blocks, grid-stride over query rows.
//   Phase 1: 4-deep unrolled float4 scan of the adjacency row (MLP), push
//            nonzero (j, e) into LDS neighbor list (avg degree ~4).
//   Phase 2: thread 0 computes the stable softmax over {self} U neighbors.
//   Phase 3: 128 threads accumulate h[f] = w_self*q[f] + sum_j w_j*k[j][f],
//            apply elu, write out.
// ---------------------------------------------------------------------------
__global__ __launch_bounds__(256)
void gat_row_kernel(const int* __restrict__ version,
                    const float* __restrict__ U9,
                    const float* __restrict__ U10,
                    const float* __restrict__ adj9to10,
                    const float* __restrict__ adj10to9,
                    const float* __restrict__ qa1,
                    const float* __restrict__ qa2,
                    const float* __restrict__ ka2,
                    float* __restrict__ out) {
    const int v  = version[0];
    const int nq = v ? N10 : N9;
    const int nk = v ? N9  : N10;

    const float* __restrict__ Q      = v ? U10 : U9;
    const float* __restrict__ K      = v ? U9  : U10;
    const float* __restrict__ adjmat = v ? adj10to9 : adj9to10;

    __shared__ int   s_cnt;
    __shared__ float s_wself;
    __shared__ int   s_j[MAXNBR];
    __shared__ float s_e[MAXNBR];
    __shared__ float s_w[MAXNBR];

    const int t  = threadIdx.x;
    const int n4 = nk >> 2;

    for (int i = blockIdx.x; i < nq; i += gridDim.x) {
        if (t == 0) s_cnt = 0;
        __syncthreads();

        const float qa1i = qa1[i];
        const float4* __restrict__ adj4 = (const float4*)(adjmat + (size_t)i * nk);

        // Phase 1: 4-deep unrolled scan — 4 loads in flight per thread.
        for (int p0 = t; p0 < n4; p0 += 256 * 4) {
            const int p1 = p0 + 256, p2 = p0 + 512, p3 = p0 + 768;
            float4 r0 = adj4[p0];
            float4 r1 = make_float4(0.f, 0.f, 0.f, 0.f);
            float4 r2 = r1, r3 = r1;
            if (p1 < n4) r1 = adj4[p1];
            if (p2 < n4) r2 = adj4[p2];
            if (p3 < n4) r3 = adj4[p3];

            float4 rr[4] = {r0, r1, r2, r3};
            int    pp[4] = {p0, p1, p2, p3};
            #pragma unroll
            for (int u = 0; u < 4; ++u) {
                float4 vv = rr[u];
                if (vv.x > 0.f || vv.y > 0.f || vv.z > 0.f || vv.w > 0.f) {
                    float va[4] = {vv.x, vv.y, vv.z, vv.w};
                    #pragma unroll
                    for (int c = 0; c < 4; ++c) {
                        if (va[c] > 0.f) {
                            int idx = atomicAdd(&s_cnt, 1);
                            if (idx < MAXNBR) {
                                int j = pp[u] * 4 + c;
                                float e = qa1i + ka2[j];
                                e = (e >= 0.f) ? e : ALPHA * e;
                                s_j[idx] = j;
                                s_e[idx] = e;
                            }
                        }
                    }
                }
            }
        }
        __syncthreads();

        const int cnt = (s_cnt < MAXNBR) ? s_cnt : MAXNBR;

        // Phase 2: small softmax (self entry always unmasked -> no NaN path)
        if (t == 0) {
            float se = qa1i + qa2[i];
            se = (se >= 0.f) ? se : ALPHA * se;
            float m = se;
            for (int c = 0; c < cnt; ++c) m = fmaxf(m, s_e[c]);
            float wself = expf(se - m);
            float wsum  = wself;
            for (int c = 0; c < cnt; ++c) {
                float w = expf(s_e[c] - m);
                s_w[c] = w;
                wsum += w;
            }
            float inv = 1.f / wsum;
            s_wself = wself * inv;
            for (int c = 0; c < cnt; ++c) s_w[c] *= inv;
        }
        __syncthreads();

        // Phase 3: weighted feature accumulation + elu
        if (t < FDIM) {
            float h = s_wself * Q[(size_t)i * FDIM + t];
            for (int c = 0; c < cnt; ++c) {
                h += s_w[c] * K[(size_t)s_j[c] * FDIM + t];
            }
            h = (h > 0.f) ? h : expm1f(h);
            out[(size_t)i * FDIM + t] = h;
        }
        __syncthreads();  // protect s_* reuse for next row
    }
}

extern "C" void kernel_launch(void* const* d_in, const int* in_sizes, int n_in,
                              void* d_out, int out_size, void* d_ws, size_t ws_size,
                              hipStream_t stream) {
    const int*   d_version = (const int*)d_in[0];
    const float* d_U9      = (const float*)d_in[1];
    const float* d_U10     = (const float*)d_in[2];
    const float* d_a       = (const float*)d_in[3];
    const float* d_adj9    = (const float*)d_in[4];
    const float* d_adj10   = (const float*)d_in[5];
    float*       d_o       = (float*)d_out;

    // Workspace layout (floats): qa1[9000] | qa2[9000] | ka2[9000]
    float* w_qa1 = (float*)d_ws;
    float* w_qa2 = w_qa1 + N10;
    float* w_ka2 = w_qa2 + N10;

    // Kernel A: dots for all query + key nodes (N9 + N10 blocks covers both
    // version branches; extents resolved on-device).
    gat_dots_kernel<<<N9 + N10, 64, 0, stream>>>(
        d_version, d_U9, d_U10, d_a, w_qa1, w_qa2, w_ka2);

    // Kernel B: persistent blocks, grid-stride over rows.
    gat_row_kernel<<<ROWBLOCKS, 256, 0, stream>>>(
        d_version, d_U9, d_U10, d_adj9, d_adj10,
        w_qa1, w_qa2, w_ka2, d_o);
}